// Round 4
// baseline (320.983 us; speedup 1.0000x reference)
//
#include <hip/hip_runtime.h>
#include <hip/hip_bf16.h>
#include <stdint.h>

typedef __attribute__((ext_vector_type(8))) short bf16x8;
typedef __attribute__((ext_vector_type(4))) float f32x4;
typedef __attribute__((ext_vector_type(8))) unsigned short ushort8;

__device__ __forceinline__ float bf2f(unsigned short u) {
  union { unsigned int i; float f; } x; x.i = ((unsigned int)u) << 16; return x.f;
}
__device__ __forceinline__ unsigned short f2bf(float f) {
  union { __hip_bfloat16 h; unsigned short u; } x; x.h = __float2bfloat16(f); return x.u;
}

__device__ __forceinline__ void gload_lds16(const void* g, void* l) {
  __builtin_amdgcn_global_load_lds((__attribute__((address_space(1))) const void*)g,
                                   (__attribute__((address_space(3))) void*)l, 16, 0, 0);
}

// ---------------- f32 -> bf16 convert (weights only) ----------------
__global__ __launch_bounds__(256) void cvt3_kernel(const float* __restrict__ a,
                                                   const float* __restrict__ b,
                                                   const float* __restrict__ c,
                                                   unsigned short* __restrict__ oa,
                                                   unsigned short* __restrict__ ob,
                                                   unsigned short* __restrict__ oc,
                                                   int n8) {
  const float* in = blockIdx.y == 0 ? a : blockIdx.y == 1 ? b : c;
  unsigned short* out = blockIdx.y == 0 ? oa : blockIdx.y == 1 ? ob : oc;
  int i = blockIdx.x * 256 + threadIdx.x;
  if (i >= n8) return;
  const float4* p = (const float4*)(in + (size_t)i * 8);
  float4 x = p[0], y = p[1];
  ushort8 o;
  o[0] = f2bf(x.x); o[1] = f2bf(x.y); o[2] = f2bf(x.z); o[3] = f2bf(x.w);
  o[4] = f2bf(y.x); o[5] = f2bf(y.y); o[6] = f2bf(y.z); o[7] = f2bf(y.w);
  *(ushort8*)(out + (size_t)i * 8) = o;
}

// ============ projection GEMM with f32-A reg-staging + fused bias+L2norm ============
// C_norm[M,1024] = l2norm_per_head( A_f32[M,1024] @ W_bf16[1024,1024]^T + bias )
// z=2 batch (k->kh, v->vh). 128x128 tile, BK=32, dbuf, 4 waves.
__global__ __launch_bounds__(256) void proj_norm_kernel(
    const float* __restrict__ A0, const float* __restrict__ A1,
    const unsigned short* __restrict__ B0, const unsigned short* __restrict__ B1,
    const float* __restrict__ bias0, const float* __restrict__ bias1,
    unsigned short* __restrict__ C0, unsigned short* __restrict__ C1) {
  __shared__ unsigned short Ab[2][128][32];
  __shared__ unsigned short Bb[2][128][32];

  const int flat = (blockIdx.z * 128 + blockIdx.y) * 8 + blockIdx.x;  // 2048
  const int swz = (flat & 7) * 256 + (flat >> 3);
  const int zz = swz >> 10;
  const int rem = swz & 1023;
  const int bm = rem >> 3, bn = rem & 7;
  const float* A = zz ? A1 : A0;
  const unsigned short* B = zz ? B1 : B0;
  const float* bias = zz ? bias1 : bias0;
  unsigned short* C = zz ? C1 : C0;

  const int tid = threadIdx.x, wid = tid >> 6, lane = tid & 63;
  const int wrow = (wid >> 1) * 64, wcol = (wid & 1) * 64;
  const int fr = lane & 15, fk = (lane >> 4) * 8, g4 = (lane >> 4) * 4;

  f32x4 acc[4][4];
#pragma unroll
  for (int m = 0; m < 4; ++m)
#pragma unroll
    for (int n = 0; n < 4; ++n) acc[m][n] = (f32x4){0.f, 0.f, 0.f, 0.f};

  const size_t abase = (size_t)(bm * 128) * 1024;
  const size_t bbase = (size_t)(bn * 128) * 1024;

  float4 ra[2][2];  // A prefetch regs: 2 chunks x 8 floats

#define LOADA(kt)                                                              \
  _Pragma("unroll") for (int it = 0; it < 2; ++it) {                           \
    const int idx = it * 256 + tid;                                            \
    const float* src = A + abase + (size_t)(idx >> 2) * 1024 + (kt) + (idx & 3) * 8; \
    ra[it][0] = *(const float4*)src;                                           \
    ra[it][1] = *(const float4*)(src + 4);                                     \
  }
#define WRITEA(buf)                                                            \
  _Pragma("unroll") for (int it = 0; it < 2; ++it) {                           \
    const int idx = it * 256 + tid;                                            \
    ushort8 o;                                                                 \
    _Pragma("unroll") for (int u = 0; u < 4; ++u) {                            \
      o[u] = f2bf(((const float*)&ra[it][0])[u]);                              \
      o[u + 4] = f2bf(((const float*)&ra[it][1])[u]);                          \
    }                                                                          \
    *(ushort8*)((unsigned short*)Ab[buf] + idx * 8) = o;                       \
  }
#define STAGEB(buf, kt)                                                        \
  _Pragma("unroll") for (int it = 0; it < 2; ++it) {                           \
    const int chunk = wid * 2 + it;                                            \
    gload_lds16(B + bbase + (size_t)(chunk * 16 + (lane >> 2)) * 1024 + (kt) + (lane & 3) * 8, \
                &Bb[buf][chunk * 16][0]);                                      \
  }

  STAGEB(0, 0);
  LOADA(0);
  WRITEA(0);
  __syncthreads();

  for (int t = 0; t < 32; ++t) {
    const int cur = t & 1, nxt = cur ^ 1;
    if (t < 31) {
      STAGEB(nxt, (t + 1) * 32);
      LOADA((t + 1) * 32);
    }
    bf16x8 af[4], bfv[4];
#pragma unroll
    for (int m = 0; m < 4; ++m) af[m] = *(const bf16x8*)&Ab[cur][wrow + m * 16 + fr][fk];
#pragma unroll
    for (int n = 0; n < 4; ++n) bfv[n] = *(const bf16x8*)&Bb[cur][wcol + n * 16 + fr][fk];
#pragma unroll
    for (int m = 0; m < 4; ++m)
#pragma unroll
      for (int n = 0; n < 4; ++n)
        acc[m][n] = __builtin_amdgcn_mfma_f32_16x16x32_bf16(af[m], bfv[n], acc[m][n], 0, 0, 0);
    if (t < 31) WRITEA(nxt);
    __syncthreads();
  }
#undef LOADA
#undef WRITEA
#undef STAGEB

  // ---- epilogue: bias + per-row L2 norm over this wave's 64-col head block ----
  float bsv[4];
#pragma unroll
  for (int n = 0; n < 4; ++n) bsv[n] = bias[bn * 128 + wcol + n * 16 + fr];
#pragma unroll
  for (int m = 0; m < 4; ++m) {
    float val[4][4];  // [n][j]
    float inv[4];
#pragma unroll
    for (int j = 0; j < 4; ++j) {
      float s = 0.f;
#pragma unroll
      for (int n = 0; n < 4; ++n) {
        val[n][j] = acc[m][n][j] + bsv[n];
        s += val[n][j] * val[n][j];
      }
      s += __shfl_xor(s, 1); s += __shfl_xor(s, 2);
      s += __shfl_xor(s, 4); s += __shfl_xor(s, 8);
      inv[j] = 1.f / fmaxf(sqrtf(s), 1e-12f);
    }
#pragma unroll
    for (int n = 0; n < 4; ++n) {
      const int col = bn * 128 + wcol + n * 16 + fr;
#pragma unroll
      for (int j = 0; j < 4; ++j) {
        const int row = bm * 128 + wrow + m * 16 + g4 + j;
        C[(size_t)row * 1024 + col] = f2bf(val[n][j] * inv[j]);
      }
    }
  }
}

// ============ kv partials: kvp[chunk][b][h][i][j] = sum_{s in chunk} kh[s][i]*vh[s][j] ============
// grid (16 chunks, 16 h, 4 b), 256 thr = 4 waves (one i-tile each). Deterministic, no atomics.
__global__ __launch_bounds__(256) void kv_part_kernel(const unsigned short* __restrict__ kh,
                                                      const unsigned short* __restrict__ vh,
                                                      float* __restrict__ kvp) {
  const int chunk = blockIdx.x, h = blockIdx.y, b = blockIdx.z;
  __shared__ unsigned short khT[64][264];
  __shared__ unsigned short vhT[64][264];
  const int tid = threadIdx.x, wid = tid >> 6, lane = tid & 63;
  const int fr = lane & 15, fk = (lane >> 4) * 8, g4 = (lane >> 4) * 4;

  // stage with 8x8 in-register transpose; thread t: j-block = t&7, s-block = t>>3
  const int jb = tid & 7, sb = tid >> 3;
  const size_t base = ((size_t)b * 4096 + chunk * 256) * 1024 + h * 64;
  {
    ushort8 rk[8], rv[8];
#pragma unroll
    for (int u = 0; u < 8; ++u) {
      rk[u] = *(const ushort8*)(kh + base + (size_t)(sb * 8 + u) * 1024 + jb * 8);
      rv[u] = *(const ushort8*)(vh + base + (size_t)(sb * 8 + u) * 1024 + jb * 8);
    }
#pragma unroll
    for (int jj = 0; jj < 8; ++jj) {
      ushort8 ck, cv;
#pragma unroll
      for (int u = 0; u < 8; ++u) { ck[u] = rk[u][jj]; cv[u] = rv[u][jj]; }
      *(ushort8*)&khT[jb * 8 + jj][sb * 8] = ck;
      *(ushort8*)&vhT[jb * 8 + jj][sb * 8] = cv;
    }
  }
  __syncthreads();

  f32x4 acc2[4];
#pragma unroll
  for (int n = 0; n < 4; ++n) acc2[n] = (f32x4){0.f, 0.f, 0.f, 0.f};
#pragma unroll
  for (int ks = 0; ks < 8; ++ks) {
    bf16x8 a2 = *(const bf16x8*)&khT[wid * 16 + fr][ks * 32 + fk];
    bf16x8 b2[4];
#pragma unroll
    for (int jt = 0; jt < 4; ++jt) b2[jt] = *(const bf16x8*)&vhT[jt * 16 + fr][ks * 32 + fk];
#pragma unroll
    for (int jt = 0; jt < 4; ++jt)
      acc2[jt] = __builtin_amdgcn_mfma_f32_16x16x32_bf16(a2, b2[jt], acc2[jt], 0, 0, 0);
  }
  float* dst = kvp + ((size_t)chunk * 64 + b * 16 + h) * 4096;
#pragma unroll
  for (int jt = 0; jt < 4; ++jt)
#pragma unroll
    for (int jj = 0; jj < 4; ++jj)
      dst[(wid * 16 + g4 + jj) * 64 + jt * 16 + fr] = acc2[jt][jj];
}

// ============ reduce 16 chunk-partials -> kvb[b*16+h][4096] ============
__global__ __launch_bounds__(256) void kv_reduce_kernel(const float* __restrict__ kvp,
                                                        float* __restrict__ kvb) {
  const int bh = blockIdx.x;  // 0..63
  for (int e = threadIdx.x; e < 4096; e += 256) {
    float s = 0.f;
#pragma unroll
    for (int c = 0; c < 16; ++c) s += kvp[((size_t)c * 64 + bh) * 4096 + e];
    kvb[(size_t)bh * 4096 + e] = s;
  }
}

// ============ Beff[b][h*64+j][d] = sum_i Wq[h*64+i][d]*kv[b,h,i,j]; beff = bq @ kv ============
__global__ __launch_bounds__(256) void weff_kernel(
    const unsigned short* __restrict__ Wq,
    const float* __restrict__ bq,
    const float* __restrict__ kv,
    unsigned short* __restrict__ Beff,
    float* __restrict__ beff) {
  const int dt = blockIdx.x, h = blockIdx.y, b = blockIdx.z;
  __shared__ float kvS[64 * 64];
  __shared__ float WqF[64 * 128];
  const int tid = threadIdx.x;

  const float* kvsrc = kv + ((size_t)(b * 16 + h)) * 4096;
  for (int e = tid; e < 4096; e += 256) kvS[e] = kvsrc[e];
  {
    int i = tid >> 2, dseg = tid & 3;
    const unsigned short* src = Wq + (size_t)(h * 64 + i) * 1024 + dt * 128 + dseg * 32;
    float* dst = &WqF[i * 128 + dseg * 32];
#pragma unroll
    for (int w = 0; w < 4; ++w) {
      ushort8 vv = ((const ushort8*)src)[w];
#pragma unroll
      for (int u = 0; u < 8; ++u) dst[w * 8 + u] = bf2f(vv[u]);
    }
  }
  __syncthreads();

  const int tj = tid & 63, tg = tid >> 6;
  float o[32];
#pragma unroll
  for (int dd = 0; dd < 32; ++dd) o[dd] = 0.f;
  for (int i = 0; i < 64; ++i) {
    float kvv = kvS[i * 64 + tj];
    const float* wr = &WqF[i * 128 + tg * 32];
#pragma unroll
    for (int dd = 0; dd < 32; ++dd) o[dd] += wr[dd] * kvv;
  }
  unsigned short* dstB = Beff + ((size_t)(b * 1024 + h * 64 + tj)) * 1024 + dt * 128 + tg * 32;
#pragma unroll
  for (int w = 0; w < 4; ++w) {
    ushort8 ov;
#pragma unroll
    for (int u = 0; u < 8; ++u) ov[u] = f2bf(o[w * 8 + u]);
    ((ushort8*)dstB)[w] = ov;
  }
  if (tg == 0 && dt == 0) {
    float s = 0.f;
    for (int i = 0; i < 64; ++i) s += bq[h * 64 + i] * kvS[i * 64 + tj];
    beff[b * 1024 + h * 64 + tj] = s;
  }
}

// ============ final GEMM: out = q_f32 @ Beff_b^T + beff_b (f32 out), f32-A reg-staged, dbuf ============
__global__ __launch_bounds__(256) void final_gemm_kernel(
    const float* __restrict__ A,              // q f32 [16384][1024]
    const unsigned short* __restrict__ Beff,  // [4][1024][1024] bf16
    const float* __restrict__ beff,           // [4][1024]
    float* __restrict__ out) {
  __shared__ unsigned short Ab[2][128][32];
  __shared__ unsigned short Bb[2][128][32];
  const int flat = blockIdx.y * 8 + blockIdx.x;  // 1024
  const int swz = (flat & 7) * 128 + (flat >> 3);
  const int bm = swz >> 3, bn = swz & 7;
  const int b = bm >> 5;
  const unsigned short* B = Beff + (size_t)b * 1048576;
  const float* bias = beff + b * 1024;

  const int tid = threadIdx.x, wid = tid >> 6, lane = tid & 63;
  const int wrow = (wid >> 1) * 64, wcol = (wid & 1) * 64;
  const int fr = lane & 15, fk = (lane >> 4) * 8, g4 = (lane >> 4) * 4;

  f32x4 acc[4][4];
#pragma unroll
  for (int m = 0; m < 4; ++m)
#pragma unroll
    for (int n = 0; n < 4; ++n) acc[m][n] = (f32x4){0.f, 0.f, 0.f, 0.f};

  const size_t abase = (size_t)(bm * 128) * 1024;
  const size_t bbase = (size_t)(bn * 128) * 1024;

  float4 ra[2][2];

#define LOADA(kt)                                                              \
  _Pragma("unroll") for (int it = 0; it < 2; ++it) {                           \
    const int idx = it * 256 + tid;                                            \
    const float* src = A + abase + (size_t)(idx >> 2) * 1024 + (kt) + (idx & 3) * 8; \
    ra[it][0] = *(const float4*)src;                                           \
    ra[it][1] = *(const float4*)(src + 4);                                     \
  }
#define WRITEA(buf)                                                            \
  _Pragma("unroll") for (int it = 0; it < 2; ++it) {                           \
    const int idx = it * 256 + tid;                                            \
    ushort8 o;                                                                 \
    _Pragma("unroll") for (int u = 0; u < 4; ++u) {                            \
      o[u] = f2bf(((const float*)&ra[it][0])[u]);                              \
      o[u + 4] = f2bf(((const float*)&ra[it][1])[u]);                          \
    }                                                                          \
    *(ushort8*)((unsigned short*)Ab[buf] + idx * 8) = o;                       \
  }
#define STAGEB(buf, kt)                                                        \
  _Pragma("unroll") for (int it = 0; it < 2; ++it) {                           \
    const int chunk = wid * 2 + it;                                            \
    gload_lds16(B + bbase + (size_t)(chunk * 16 + (lane >> 2)) * 1024 + (kt) + (lane & 3) * 8, \
                &Bb[buf][chunk * 16][0]);                                      \
  }

  STAGEB(0, 0);
  LOADA(0);
  WRITEA(0);
  __syncthreads();

  for (int t = 0; t < 32; ++t) {
    const int cur = t & 1, nxt = cur ^ 1;
    if (t < 31) {
      STAGEB(nxt, (t + 1) * 32);
      LOADA((t + 1) * 32);
    }
    bf16x8 af[4], bfv[4];
#pragma unroll
    for (int m = 0; m < 4; ++m) af[m] = *(const bf16x8*)&Ab[cur][wrow + m * 16 + fr][fk];
#pragma unroll
    for (int n = 0; n < 4; ++n) bfv[n] = *(const bf16x8*)&Bb[cur][wcol + n * 16 + fr][fk];
#pragma unroll
    for (int m = 0; m < 4; ++m)
#pragma unroll
      for (int n = 0; n < 4; ++n)
        acc[m][n] = __builtin_amdgcn_mfma_f32_16x16x32_bf16(af[m], bfv[n], acc[m][n], 0, 0, 0);
    if (t < 31) WRITEA(nxt);
    __syncthreads();
  }
#undef LOADA
#undef WRITEA
#undef STAGEB

#pragma unroll
  for (int n = 0; n < 4; ++n) {
    const int col = bn * 128 + wcol + n * 16 + fr;
    const float bsv = bias[col];
#pragma unroll
    for (int m = 0; m < 4; ++m) {
#pragma unroll
      for (int j = 0; j < 4; ++j) {
        const int row = bm * 128 + wrow + m * 16 + g4 + j;
        out[(size_t)row * 1024 + col] = acc[m][n][j] + bsv;
      }
    }
  }
}

extern "C" void kernel_launch(void* const* d_in, const int* in_sizes, int n_in,
                              void* d_out, int out_size, void* d_ws, size_t ws_size,
                              hipStream_t stream) {
  const float* q = (const float*)d_in[0];
  const float* k = (const float*)d_in[1];
  const float* v = (const float*)d_in[2];
  const float* Wq = (const float*)d_in[3];
  const float* bq = (const float*)d_in[4];
  const float* Wk = (const float*)d_in[5];
  const float* bk = (const float*)d_in[6];
  const float* Wv = (const float*)d_in[7];
  const float* bv = (const float*)d_in[8];
  float* out = (float*)d_out;

  char* ws = (char*)d_ws;
  const size_t MB = 1048576;
  unsigned short* kh = (unsigned short*)(ws + 0 * MB);          // 32 MB
  unsigned short* vh = (unsigned short*)(ws + 32 * MB);         // 32 MB
  unsigned short* Beff = (unsigned short*)(ws + 64 * MB);       // 8 MB
  unsigned short* Wqb = (unsigned short*)(ws + 72 * MB);        // 2 MB
  unsigned short* Wkb = (unsigned short*)(ws + 74 * MB);        // 2 MB
  unsigned short* Wvb = (unsigned short*)(ws + 76 * MB);        // 2 MB
  float* kvp = (float*)(ws + 78 * MB);                          // 16 MB
  float* kvb = (float*)(ws + 94 * MB);                          // 1 MB
  float* beff = (float*)(ws + 95 * MB);                         // 16 KB

  // 1) convert weights to bf16 (tiny)
  cvt3_kernel<<<dim3(512, 3), 256, 0, stream>>>(Wq, Wk, Wv, Wqb, Wkb, Wvb, 131072);

  // 2) projections + bias + L2 norm (reads f32 k/v directly)
  proj_norm_kernel<<<dim3(8, 128, 2), 256, 0, stream>>>(k, v, Wkb, Wvb, bk, bv, kh, vh);

  // 3) kv partials + reduce (deterministic)
  kv_part_kernel<<<dim3(16, 16, 4), 256, 0, stream>>>(kh, vh, kvp);
  kv_reduce_kernel<<<64, 256, 0, stream>>>(kvp, kvb);

  // 4) Beff = Wq-folded kv (bf16), beff = bq @ kv
  weff_kernel<<<dim3(8, 16, 4), 256, 0, stream>>>(Wqb, bq, kvb, Beff, beff);

  // 5) out = q @ Beff^T + beff (reads f32 q directly, f32 out)
  final_gemm_kernel<<<dim3(8, 128), 256, 0, stream>>>(q, Beff, beff, out);
}